// Round 1
// 1007.823 us; speedup vs baseline: 2.2474x; 2.2474x over previous
//
#include <hip/hip_runtime.h>
#include <hip/hip_bf16.h>

#define BB 8
#define SS 2048
#define DD 384
#define HH 8
#define HD 48
#define QT 16
#define KT 32

typedef unsigned short u16;
typedef unsigned short u16x4 __attribute__((ext_vector_type(4)));
typedef unsigned short u16x8 __attribute__((ext_vector_type(8)));
typedef short s16x8 __attribute__((ext_vector_type(8)));
typedef float f32x4 __attribute__((ext_vector_type(4)));

__device__ __forceinline__ float bf2f(u16 v){
  union { unsigned int u; float f; } x; x.u = ((unsigned int)v) << 16; return x.f;
}
__device__ __forceinline__ u16 f2bf(float f){
  union { float f; unsigned int u; } x; x.f = f;
  unsigned int r = x.u + 0x7fffu + ((x.u >> 16) & 1u);
  return (u16)(r >> 16);
}

// ---------------- Kernel 1: fused QKV projection ----------------
__global__ __launch_bounds__(384, 2) void qkv_kernel(
    const float* __restrict__ x, const float* __restrict__ Wqkv,
    const float* __restrict__ bqkv,
    u16* __restrict__ Q, u16* __restrict__ K, u16* __restrict__ V)
{
  __shared__ float4 xs4[8*96];
  const int tid = threadIdx.x;
  const long row0 = (long)blockIdx.x * 8;
  const float4* xg = (const float4*)(x + row0*DD);
  for (int i = tid; i < 768; i += 384) xs4[i] = xg[i];
  __syncthreads();
  #pragma unroll
  for (int j = 0; j < 3; j++){
    const int e = tid + j*384;
    const float4* w = (const float4*)(Wqkv + (long)e*DD);
    float acc[8];
    #pragma unroll
    for (int r = 0; r < 8; r++) acc[r] = 0.f;
    for (int d4 = 0; d4 < 96; d4++){
      float4 a = w[d4];
      #pragma unroll
      for (int r = 0; r < 8; r++){
        float4 xv = xs4[r*96 + d4];
        acc[r] += a.x*xv.x + a.y*xv.y + a.z*xv.z + a.w*xv.w;
      }
    }
    const float bias = bqkv[e];
    const int h = e / 144, c = e % 144;
    u16* dst; int cc;
    if (c < 48){ dst = Q; cc = c; }
    else if (c < 96){ dst = K; cc = c - 48; }
    else { dst = V; cc = c - 96; }
    #pragma unroll
    for (int r = 0; r < 8; r++){
      const long row = row0 + r;
      const int bb = (int)(row >> 11), s = (int)(row & 2047);
      dst[(((long)(bb*HH + h))*SS + s)*HD + cc] = f2bf(acc[r] + bias);
    }
  }
}

// ---------------- Kernel 2: MFMA attention with head-softmax ----------------
// Block: one (b, 16-query tile). 8 waves = 8 heads.
// Per 32-key tile: QK^T via mfma_16x16x32_bf16 (d padded 48->64, K from global),
// 8-head softmax per (q,k) by 512 threads, PV via mfma with LDS-transposed V.
__global__ __launch_bounds__(512, 4) void attn_kernel(
    const u16* __restrict__ Q, const u16* __restrict__ K,
    const u16* __restrict__ V, float* __restrict__ vals)
{
  __shared__ float Ss[HH][QT][36];   // scores f32 [h][q][k], 36-pad rows
  __shared__ u16  Pb[HH][QT][40];    // P bf16 [h][q][k], 40-pad (80B rows, 16B-aligned)
  __shared__ u16  Vt[HH][HD][40];    // V^T bf16 [h][d][k]

  const int tid  = threadIdx.x;
  const int w    = tid >> 6;         // wave id == head
  const int lane = tid & 63;
  const int h    = w;
  const int b    = blockIdx.x >> 7;
  const int qt   = blockIdx.x & 127;
  const int q0   = qt * QT;
  const int lg   = lane >> 4;        // 4 lane-groups (k-dim octet index)
  const int ln   = lane & 15;        // row/col within 16x16 tile

  const long hbase = ((long)(b*HH + h)) * SS;

  // Q fragments (A operand), held for the whole kernel. d padded to 64 with zeros.
  s16x8 qf0, qf1;
  {
    const u16* qp = Q + (hbase + q0 + ln)*HD;
    qf0 = *(const s16x8*)(qp + lg*8);
    if (lane < 32) qf1 = *(const s16x8*)(qp + 32 + lg*8);
    else           qf1 = (s16x8){0,0,0,0,0,0,0,0};
  }

  f32x4 oacc[3];
  #pragma unroll
  for (int i = 0; i < 3; i++) oacc[i] = (f32x4){0.f,0.f,0.f,0.f};

  const float scale = 0.14433756729740643f;  // 1/sqrt(48)

  // softmax thread mapping: one (q,k) pair per thread
  const int sq = tid >> 5, sk = tid & 31;
  // V staging mapping: each wave stages its own head; 2 threads per k-row
  const int vk = (tid >> 1) & 31, vhalf = tid & 1;

  for (int kt = 0; kt < SS/KT; kt++){
    const int k0 = kt * KT;
    __syncthreads();   // prev iter's PV done reading Pb/Vt; softmax done with Ss

    // --- QK^T: S[h][16q][32k] per wave ---
    #pragma unroll
    for (int nt = 0; nt < 2; nt++){
      const u16* kp = K + (hbase + k0 + nt*16 + ln)*HD;
      s16x8 kf0 = *(const s16x8*)(kp + lg*8);
      s16x8 kf1;
      if (lane < 32) kf1 = *(const s16x8*)(kp + 32 + lg*8);
      else           kf1 = (s16x8){0,0,0,0,0,0,0,0};
      f32x4 a = (f32x4){0.f,0.f,0.f,0.f};
      a = __builtin_amdgcn_mfma_f32_16x16x32_bf16(qf0, kf0, a, 0, 0, 0);
      a = __builtin_amdgcn_mfma_f32_16x16x32_bf16(qf1, kf1, a, 0, 0, 0);
      #pragma unroll
      for (int r = 0; r < 4; r++)
        Ss[h][lg*4 + r][nt*16 + ln] = a[r] * scale;
    }

    // --- stage V transposed: Vt[h][d][k]; wave h stages its own head ---
    {
      const u16* vp = V + (hbase + k0 + vk)*HD + vhalf*24;
      u16x8 v0 = *(const u16x8*)(vp);
      u16x8 v1 = *(const u16x8*)(vp + 8);
      u16x8 v2 = *(const u16x8*)(vp + 16);
      const int d0 = vhalf*24;
      #pragma unroll
      for (int j = 0; j < 8; j++){
        Vt[h][d0 +      j][vk] = v0[j];
        Vt[h][d0 + 8  + j][vk] = v1[j];
        Vt[h][d0 + 16 + j][vk] = v2[j];
      }
    }
    __syncthreads();

    // --- softmax over the 8 heads for my (q,k) ---
    {
      float s0 = Ss[0][sq][sk], s1 = Ss[1][sq][sk];
      float s2 = Ss[2][sq][sk], s3 = Ss[3][sq][sk];
      float s4 = Ss[4][sq][sk], s5 = Ss[5][sq][sk];
      float s6 = Ss[6][sq][sk], s7 = Ss[7][sq][sk];
      float m = fmaxf(fmaxf(fmaxf(s0,s1), fmaxf(s2,s3)),
                      fmaxf(fmaxf(s4,s5), fmaxf(s6,s7)));
      float e0 = __expf(s0-m), e1 = __expf(s1-m), e2 = __expf(s2-m), e3 = __expf(s3-m);
      float e4 = __expf(s4-m), e5 = __expf(s5-m), e6 = __expf(s6-m), e7 = __expf(s7-m);
      float rs = 1.f / (e0+e1+e2+e3+e4+e5+e6+e7);
      Pb[0][sq][sk] = f2bf(e0*rs); Pb[1][sq][sk] = f2bf(e1*rs);
      Pb[2][sq][sk] = f2bf(e2*rs); Pb[3][sq][sk] = f2bf(e3*rs);
      Pb[4][sq][sk] = f2bf(e4*rs); Pb[5][sq][sk] = f2bf(e5*rs);
      Pb[6][sq][sk] = f2bf(e6*rs); Pb[7][sq][sk] = f2bf(e7*rs);
    }
    __syncthreads();

    // --- PV: O[16q][48d] += P[16q][32k] * V[32k][48d] ---
    {
      s16x8 pf = *(const s16x8*)&Pb[h][ln][lg*8];
      #pragma unroll
      for (int nt = 0; nt < 3; nt++){
        s16x8 vf = *(const s16x8*)&Vt[h][nt*16 + ln][lg*8];
        oacc[nt] = __builtin_amdgcn_mfma_f32_16x16x32_bf16(pf, vf, oacc[nt], 0, 0, 0);
      }
    }
  }

  // store vals[b][h][q][d] fp32 (bug-compatible flat layout, same as before)
  float* op = vals + (hbase + q0)*HD;
  #pragma unroll
  for (int nt = 0; nt < 3; nt++)
    #pragma unroll
    for (int r = 0; r < 4; r++)
      op[(long)(lg*4 + r)*HD + nt*16 + ln] = oacc[nt][r];
}

// ---------------- Kernel 3: output projection ----------------
__global__ __launch_bounds__(384, 2) void out_kernel(
    const float* __restrict__ vals, const float* __restrict__ Wo,
    const float* __restrict__ bo, float* __restrict__ out)
{
  __shared__ float4 vs4[8*96];
  const int tid = threadIdx.x;
  const long row0 = (long)blockIdx.x * 8;
  const float4* vg = (const float4*)(vals + row0*DD);
  for (int i = tid; i < 768; i += 384) vs4[i] = vg[i];
  __syncthreads();
  const float4* w = (const float4*)(Wo + (long)tid*DD);
  float acc[8];
  #pragma unroll
  for (int r = 0; r < 8; r++) acc[r] = 0.f;
  for (int d4 = 0; d4 < 96; d4++){
    float4 a = w[d4];
    #pragma unroll
    for (int r = 0; r < 8; r++){
      float4 xv = vs4[r*96 + d4];
      acc[r] += a.x*xv.x + a.y*xv.y + a.z*xv.z + a.w*xv.w;
    }
  }
  const float bias = bo[tid];
  #pragma unroll
  for (int r = 0; r < 8; r++)
    out[(row0 + r)*DD + tid] = acc[r] + bias;
}

extern "C" void kernel_launch(void* const* d_in, const int* in_sizes, int n_in,
                              void* d_out, int out_size, void* d_ws, size_t ws_size,
                              hipStream_t stream)
{
  const float* x    = (const float*)d_in[0];
  const float* Wqkv = (const float*)d_in[1];
  const float* bqkv = (const float*)d_in[2];
  const float* Wo   = (const float*)d_in[3];
  const float* bo   = (const float*)d_in[4];
  float* out = (float*)d_out;

  const size_t QSZ = (size_t)BB*HH*SS*HD;   // 6,291,456 elems
  u16* Q = (u16*)d_ws;
  u16* K = Q + QSZ;
  u16* V = K + QSZ;
  float* vals = (float*)(V + QSZ);          // fp32, 25.2 MB

  qkv_kernel<<<2048, 384, 0, stream>>>(x, Wqkv, bqkv, Q, K, V);
  attn_kernel<<<1024, 512, 0, stream>>>(Q, K, V, vals);
  out_kernel<<<2048, 384, 0, stream>>>(vals, Wo, bo, out);
}

// Round 2
// 371.565 us; speedup vs baseline: 6.0957x; 2.7124x over previous
//
#include <hip/hip_runtime.h>
#include <hip/hip_bf16.h>

#define BB 8
#define SS 2048
#define DD 384
#define HH 8
#define HD 48
#define QT 16
#define KT 32

typedef unsigned short u16;
typedef unsigned short u16x4 __attribute__((ext_vector_type(4)));
typedef unsigned short u16x8 __attribute__((ext_vector_type(8)));
typedef short s16x8 __attribute__((ext_vector_type(8)));
typedef float f32x4 __attribute__((ext_vector_type(4)));

__device__ __forceinline__ float bf2f(u16 v){
  union { unsigned int u; float f; } x; x.u = ((unsigned int)v) << 16; return x.f;
}
__device__ __forceinline__ u16 f2bf(float f){
  union { float f; unsigned int u; } x; x.f = f;
  unsigned int r = x.u + 0x7fffu + ((x.u >> 16) & 1u);
  return (u16)(r >> 16);
}
// split fp32 into hi (truncated bf16) + lo (bf16 of residual); hi+lo ~ 17-bit mantissa
__device__ __forceinline__ void split2(float f, u16& h, u16& l){
  union { float f; unsigned int u; } x; x.f = f;
  h = (u16)(x.u >> 16);
  l = f2bf(f - bf2f(h));
}

// ---------------- Kernel 1: QKV projection, split-bf16 MFMA GEMM ----------------
// C[16384 x 1152] = x[16384 x 384] * Wqkv^T ; scatter to Q/K/V bf16 with bias.
// 128x128 tile, 8 waves (4M x 2N), each wave 32x64 = 2x4 frags of 16x16x32.
__global__ __launch_bounds__(512, 4) void qkv_gemm(
    const float* __restrict__ x, const float* __restrict__ W,
    const float* __restrict__ bias,
    u16* __restrict__ Q, u16* __restrict__ Kd, u16* __restrict__ V)
{
  __shared__ u16 Ah[128][40], Al[128][40], Bh[128][40], Bl[128][40];
  const int tid  = threadIdx.x;
  const int w    = tid >> 6, lane = tid & 63;
  const int lg   = lane >> 4, ln = lane & 15;
  const int wm   = w >> 1, wn = w & 1;
  const int mb   = blockIdx.x / 9, nb = blockIdx.x % 9;  // adjacent blocks share x-panel
  const int m0   = mb * 128, n0 = nb * 128;
  const int srow = tid >> 3, sk4 = (tid & 7) << 2;

  f32x4 acc[8];
  #pragma unroll
  for (int i = 0; i < 8; i++) acc[i] = (f32x4){0.f,0.f,0.f,0.f};

  for (int ks = 0; ks < 12; ks++){
    const int k0 = ks * 32;
    __syncthreads();
    #pragma unroll
    for (int p = 0; p < 2; p++){
      const int row = srow + p*64;
      float4 av = *(const float4*)(x + (long)(m0+row)*DD + k0 + sk4);
      float4 bv = *(const float4*)(W + (long)(n0+row)*DD + k0 + sk4);
      u16 h0,l0,h1,l1,h2,l2,h3,l3;
      split2(av.x,h0,l0); split2(av.y,h1,l1); split2(av.z,h2,l2); split2(av.w,h3,l3);
      *(u16x4*)&Ah[row][sk4] = (u16x4){h0,h1,h2,h3};
      *(u16x4*)&Al[row][sk4] = (u16x4){l0,l1,l2,l3};
      split2(bv.x,h0,l0); split2(bv.y,h1,l1); split2(bv.z,h2,l2); split2(bv.w,h3,l3);
      *(u16x4*)&Bh[row][sk4] = (u16x4){h0,h1,h2,h3};
      *(u16x4*)&Bl[row][sk4] = (u16x4){l0,l1,l2,l3};
    }
    __syncthreads();
    s16x8 bh[4], bl[4];
    #pragma unroll
    for (int fn = 0; fn < 4; fn++){
      const int br = wn*64 + fn*16 + ln;
      bh[fn] = *(const s16x8*)&Bh[br][lg*8];
      bl[fn] = *(const s16x8*)&Bl[br][lg*8];
    }
    #pragma unroll
    for (int fm = 0; fm < 2; fm++){
      const int ar = wm*32 + fm*16 + ln;
      s16x8 ah = *(const s16x8*)&Ah[ar][lg*8];
      s16x8 al = *(const s16x8*)&Al[ar][lg*8];
      #pragma unroll
      for (int fn = 0; fn < 4; fn++){
        f32x4 c = acc[fm*4+fn];
        c = __builtin_amdgcn_mfma_f32_16x16x32_bf16(ah, bh[fn], c, 0, 0, 0);
        c = __builtin_amdgcn_mfma_f32_16x16x32_bf16(ah, bl[fn], c, 0, 0, 0);
        c = __builtin_amdgcn_mfma_f32_16x16x32_bf16(al, bh[fn], c, 0, 0, 0);
        acc[fm*4+fn] = c;
      }
    }
  }
  // epilogue: C row = lg*4+r (M), col = ln (N=e); scatter to Q/K/V bf16
  #pragma unroll
  for (int fm = 0; fm < 2; fm++){
    #pragma unroll
    for (int fn = 0; fn < 4; fn++){
      const int e = n0 + wn*64 + fn*16 + ln;
      const float bi = bias[e];
      const int h = e / 144, c = e % 144;
      u16* dst; int cc;
      if (c < 48){ dst = Q; cc = c; }
      else if (c < 96){ dst = Kd; cc = c - 48; }
      else { dst = V; cc = c - 96; }
      #pragma unroll
      for (int r = 0; r < 4; r++){
        const int mm = m0 + wm*32 + fm*16 + lg*4 + r;
        const int bb = mm >> 11, s = mm & 2047;
        dst[(((long)(bb*HH + h))*SS + s)*HD + cc] = f2bf(acc[fm*4+fn][r] + bi);
      }
    }
  }
}

// ---------------- Kernel 2: MFMA attention with head-softmax (unchanged) ----------------
__global__ __launch_bounds__(512, 4) void attn_kernel(
    const u16* __restrict__ Q, const u16* __restrict__ K,
    const u16* __restrict__ V, float* __restrict__ vals)
{
  __shared__ float Ss[HH][QT][36];
  __shared__ u16  Pb[HH][QT][40];
  __shared__ u16  Vt[HH][HD][40];

  const int tid  = threadIdx.x;
  const int w    = tid >> 6;
  const int lane = tid & 63;
  const int h    = w;
  const int b    = blockIdx.x >> 7;
  const int qt   = blockIdx.x & 127;
  const int q0   = qt * QT;
  const int lg   = lane >> 4;
  const int ln   = lane & 15;

  const long hbase = ((long)(b*HH + h)) * SS;

  s16x8 qf0, qf1;
  {
    const u16* qp = Q + (hbase + q0 + ln)*HD;
    qf0 = *(const s16x8*)(qp + lg*8);
    if (lane < 32) qf1 = *(const s16x8*)(qp + 32 + lg*8);
    else           qf1 = (s16x8){0,0,0,0,0,0,0,0};
  }

  f32x4 oacc[3];
  #pragma unroll
  for (int i = 0; i < 3; i++) oacc[i] = (f32x4){0.f,0.f,0.f,0.f};

  const float scale = 0.14433756729740643f;

  const int sq = tid >> 5, sk = tid & 31;
  const int vk = (tid >> 1) & 31, vhalf = tid & 1;

  for (int kt = 0; kt < SS/KT; kt++){
    const int k0 = kt * KT;
    __syncthreads();

    #pragma unroll
    for (int nt = 0; nt < 2; nt++){
      const u16* kp = K + (hbase + k0 + nt*16 + ln)*HD;
      s16x8 kf0 = *(const s16x8*)(kp + lg*8);
      s16x8 kf1;
      if (lane < 32) kf1 = *(const s16x8*)(kp + 32 + lg*8);
      else           kf1 = (s16x8){0,0,0,0,0,0,0,0};
      f32x4 a = (f32x4){0.f,0.f,0.f,0.f};
      a = __builtin_amdgcn_mfma_f32_16x16x32_bf16(qf0, kf0, a, 0, 0, 0);
      a = __builtin_amdgcn_mfma_f32_16x16x32_bf16(qf1, kf1, a, 0, 0, 0);
      #pragma unroll
      for (int r = 0; r < 4; r++)
        Ss[h][lg*4 + r][nt*16 + ln] = a[r] * scale;
    }

    {
      const u16* vp = V + (hbase + k0 + vk)*HD + vhalf*24;
      u16x8 v0 = *(const u16x8*)(vp);
      u16x8 v1 = *(const u16x8*)(vp + 8);
      u16x8 v2 = *(const u16x8*)(vp + 16);
      const int d0 = vhalf*24;
      #pragma unroll
      for (int j = 0; j < 8; j++){
        Vt[h][d0 +      j][vk] = v0[j];
        Vt[h][d0 + 8  + j][vk] = v1[j];
        Vt[h][d0 + 16 + j][vk] = v2[j];
      }
    }
    __syncthreads();

    {
      float s0 = Ss[0][sq][sk], s1 = Ss[1][sq][sk];
      float s2 = Ss[2][sq][sk], s3 = Ss[3][sq][sk];
      float s4 = Ss[4][sq][sk], s5 = Ss[5][sq][sk];
      float s6 = Ss[6][sq][sk], s7 = Ss[7][sq][sk];
      float m = fmaxf(fmaxf(fmaxf(s0,s1), fmaxf(s2,s3)),
                      fmaxf(fmaxf(s4,s5), fmaxf(s6,s7)));
      float e0 = __expf(s0-m), e1 = __expf(s1-m), e2 = __expf(s2-m), e3 = __expf(s3-m);
      float e4 = __expf(s4-m), e5 = __expf(s5-m), e6 = __expf(s6-m), e7 = __expf(s7-m);
      float rs = 1.f / (e0+e1+e2+e3+e4+e5+e6+e7);
      Pb[0][sq][sk] = f2bf(e0*rs); Pb[1][sq][sk] = f2bf(e1*rs);
      Pb[2][sq][sk] = f2bf(e2*rs); Pb[3][sq][sk] = f2bf(e3*rs);
      Pb[4][sq][sk] = f2bf(e4*rs); Pb[5][sq][sk] = f2bf(e5*rs);
      Pb[6][sq][sk] = f2bf(e6*rs); Pb[7][sq][sk] = f2bf(e7*rs);
    }
    __syncthreads();

    {
      s16x8 pf = *(const s16x8*)&Pb[h][ln][lg*8];
      #pragma unroll
      for (int nt = 0; nt < 3; nt++){
        s16x8 vf = *(const s16x8*)&Vt[h][nt*16 + ln][lg*8];
        oacc[nt] = __builtin_amdgcn_mfma_f32_16x16x32_bf16(pf, vf, oacc[nt], 0, 0, 0);
      }
    }
  }

  float* op = vals + (hbase + q0)*HD;
  #pragma unroll
  for (int nt = 0; nt < 3; nt++)
    #pragma unroll
    for (int r = 0; r < 4; r++)
      op[(long)(lg*4 + r)*HD + nt*16 + ln] = oacc[nt][r];
}

// ---------------- Kernel 3: output projection, split-bf16 MFMA GEMM ----------------
__global__ __launch_bounds__(512, 4) void out_gemm(
    const float* __restrict__ A, const float* __restrict__ W,
    const float* __restrict__ bias, float* __restrict__ out)
{
  __shared__ u16 Ah[128][40], Al[128][40], Bh[128][40], Bl[128][40];
  const int tid  = threadIdx.x;
  const int w    = tid >> 6, lane = tid & 63;
  const int lg   = lane >> 4, ln = lane & 15;
  const int wm   = w >> 1, wn = w & 1;
  const int mb   = blockIdx.x / 3, nb = blockIdx.x % 3;
  const int m0   = mb * 128, n0 = nb * 128;
  const int srow = tid >> 3, sk4 = (tid & 7) << 2;

  f32x4 acc[8];
  #pragma unroll
  for (int i = 0; i < 8; i++) acc[i] = (f32x4){0.f,0.f,0.f,0.f};

  for (int ks = 0; ks < 12; ks++){
    const int k0 = ks * 32;
    __syncthreads();
    #pragma unroll
    for (int p = 0; p < 2; p++){
      const int row = srow + p*64;
      float4 av = *(const float4*)(A + (long)(m0+row)*DD + k0 + sk4);
      float4 bv = *(const float4*)(W + (long)(n0+row)*DD + k0 + sk4);
      u16 h0,l0,h1,l1,h2,l2,h3,l3;
      split2(av.x,h0,l0); split2(av.y,h1,l1); split2(av.z,h2,l2); split2(av.w,h3,l3);
      *(u16x4*)&Ah[row][sk4] = (u16x4){h0,h1,h2,h3};
      *(u16x4*)&Al[row][sk4] = (u16x4){l0,l1,l2,l3};
      split2(bv.x,h0,l0); split2(bv.y,h1,l1); split2(bv.z,h2,l2); split2(bv.w,h3,l3);
      *(u16x4*)&Bh[row][sk4] = (u16x4){h0,h1,h2,h3};
      *(u16x4*)&Bl[row][sk4] = (u16x4){l0,l1,l2,l3};
    }
    __syncthreads();
    s16x8 bh[4], bl[4];
    #pragma unroll
    for (int fn = 0; fn < 4; fn++){
      const int br = wn*64 + fn*16 + ln;
      bh[fn] = *(const s16x8*)&Bh[br][lg*8];
      bl[fn] = *(const s16x8*)&Bl[br][lg*8];
    }
    #pragma unroll
    for (int fm = 0; fm < 2; fm++){
      const int ar = wm*32 + fm*16 + ln;
      s16x8 ah = *(const s16x8*)&Ah[ar][lg*8];
      s16x8 al = *(const s16x8*)&Al[ar][lg*8];
      #pragma unroll
      for (int fn = 0; fn < 4; fn++){
        f32x4 c = acc[fm*4+fn];
        c = __builtin_amdgcn_mfma_f32_16x16x32_bf16(ah, bh[fn], c, 0, 0, 0);
        c = __builtin_amdgcn_mfma_f32_16x16x32_bf16(ah, bl[fn], c, 0, 0, 0);
        c = __builtin_amdgcn_mfma_f32_16x16x32_bf16(al, bh[fn], c, 0, 0, 0);
        acc[fm*4+fn] = c;
      }
    }
  }
  #pragma unroll
  for (int fm = 0; fm < 2; fm++){
    #pragma unroll
    for (int fn = 0; fn < 4; fn++){
      const int e = n0 + wn*64 + fn*16 + ln;
      const float bi = bias[e];
      #pragma unroll
      for (int r = 0; r < 4; r++){
        const int mm = m0 + wm*32 + fm*16 + lg*4 + r;
        out[(long)mm*DD + e] = acc[fm*4+fn][r] + bi;
      }
    }
  }
}

extern "C" void kernel_launch(void* const* d_in, const int* in_sizes, int n_in,
                              void* d_out, int out_size, void* d_ws, size_t ws_size,
                              hipStream_t stream)
{
  const float* x    = (const float*)d_in[0];
  const float* Wqkv = (const float*)d_in[1];
  const float* bqkv = (const float*)d_in[2];
  const float* Wo   = (const float*)d_in[3];
  const float* bo   = (const float*)d_in[4];
  float* out = (float*)d_out;

  const size_t QSZ = (size_t)BB*HH*SS*HD;   // 6,291,456 elems
  u16* Q = (u16*)d_ws;
  u16* K = Q + QSZ;
  u16* V = K + QSZ;
  float* vals = (float*)(V + QSZ);          // fp32, 25.2 MB

  qkv_gemm<<<1152, 512, 0, stream>>>(x, Wqkv, bqkv, Q, K, V);
  attn_kernel<<<1024, 512, 0, stream>>>(Q, K, V, vals);
  out_gemm<<<384, 512, 0, stream>>>(vals, Wo, bo, out);
}

// Round 3
// 353.444 us; speedup vs baseline: 6.4082x; 1.0513x over previous
//
#include <hip/hip_runtime.h>
#include <hip/hip_bf16.h>

#define BB 8
#define SS 2048
#define DD 384
#define HH 8
#define HD 48
#define QT 16
#define KT 32

typedef unsigned short u16;
typedef unsigned short u16x4 __attribute__((ext_vector_type(4)));
typedef unsigned short u16x8 __attribute__((ext_vector_type(8)));
typedef short s16x8 __attribute__((ext_vector_type(8)));
typedef float f32x4 __attribute__((ext_vector_type(4)));

__device__ __forceinline__ float bf2f(u16 v){
  union { unsigned int u; float f; } x; x.u = ((unsigned int)v) << 16; return x.f;
}
__device__ __forceinline__ u16 f2bf(float f){
  union { float f; unsigned int u; } x; x.f = f;
  unsigned int r = x.u + 0x7fffu + ((x.u >> 16) & 1u);
  return (u16)(r >> 16);
}
// split fp32 into hi (truncated bf16) + lo (bf16 of residual); hi+lo ~ 17-bit mantissa
__device__ __forceinline__ void split2(float f, u16& h, u16& l){
  union { float f; unsigned int u; } x; x.f = f;
  h = (u16)(x.u >> 16);
  l = f2bf(f - bf2f(h));
}

// ---------------- Kernel 1: QKV projection, split-bf16 MFMA GEMM ----------------
// C[16384 x 1152] = x[16384 x 384] * Wqkv^T ; scatter to Q/K ([B,H,S,48]) and
// V^T ([B,H,48,S]) bf16 with bias.
__global__ __launch_bounds__(512, 4) void qkv_gemm(
    const float* __restrict__ x, const float* __restrict__ W,
    const float* __restrict__ bias,
    u16* __restrict__ Q, u16* __restrict__ Kd, u16* __restrict__ Vt)
{
  __shared__ u16 Ah[128][40], Al[128][40], Bh[128][40], Bl[128][40];
  const int tid  = threadIdx.x;
  const int w    = tid >> 6, lane = tid & 63;
  const int lg   = lane >> 4, ln = lane & 15;
  const int wm   = w >> 1, wn = w & 1;
  const int mb   = blockIdx.x / 9, nb = blockIdx.x % 9;
  const int m0   = mb * 128, n0 = nb * 128;
  const int srow = tid >> 3, sk4 = (tid & 7) << 2;

  f32x4 acc[8];
  #pragma unroll
  for (int i = 0; i < 8; i++) acc[i] = (f32x4){0.f,0.f,0.f,0.f};

  for (int ks = 0; ks < 12; ks++){
    const int k0 = ks * 32;
    __syncthreads();
    #pragma unroll
    for (int p = 0; p < 2; p++){
      const int row = srow + p*64;
      float4 av = *(const float4*)(x + (long)(m0+row)*DD + k0 + sk4);
      float4 bv = *(const float4*)(W + (long)(n0+row)*DD + k0 + sk4);
      u16 h0,l0,h1,l1,h2,l2,h3,l3;
      split2(av.x,h0,l0); split2(av.y,h1,l1); split2(av.z,h2,l2); split2(av.w,h3,l3);
      *(u16x4*)&Ah[row][sk4] = (u16x4){h0,h1,h2,h3};
      *(u16x4*)&Al[row][sk4] = (u16x4){l0,l1,l2,l3};
      split2(bv.x,h0,l0); split2(bv.y,h1,l1); split2(bv.z,h2,l2); split2(bv.w,h3,l3);
      *(u16x4*)&Bh[row][sk4] = (u16x4){h0,h1,h2,h3};
      *(u16x4*)&Bl[row][sk4] = (u16x4){l0,l1,l2,l3};
    }
    __syncthreads();
    s16x8 bh[4], bl[4];
    #pragma unroll
    for (int fn = 0; fn < 4; fn++){
      const int br = wn*64 + fn*16 + ln;
      bh[fn] = *(const s16x8*)&Bh[br][lg*8];
      bl[fn] = *(const s16x8*)&Bl[br][lg*8];
    }
    #pragma unroll
    for (int fm = 0; fm < 2; fm++){
      const int ar = wm*32 + fm*16 + ln;
      s16x8 ah = *(const s16x8*)&Ah[ar][lg*8];
      s16x8 al = *(const s16x8*)&Al[ar][lg*8];
      #pragma unroll
      for (int fn = 0; fn < 4; fn++){
        f32x4 c = acc[fm*4+fn];
        c = __builtin_amdgcn_mfma_f32_16x16x32_bf16(ah, bh[fn], c, 0, 0, 0);
        c = __builtin_amdgcn_mfma_f32_16x16x32_bf16(ah, bl[fn], c, 0, 0, 0);
        c = __builtin_amdgcn_mfma_f32_16x16x32_bf16(al, bh[fn], c, 0, 0, 0);
        acc[fm*4+fn] = c;
      }
    }
  }
  // epilogue: row = lg*4+r (M=token), col = ln (N=e); scatter
  #pragma unroll
  for (int fm = 0; fm < 2; fm++){
    #pragma unroll
    for (int fn = 0; fn < 4; fn++){
      const int e = n0 + wn*64 + fn*16 + ln;
      const float bi = bias[e];
      const int h = e / 144, c = e % 144;
      #pragma unroll
      for (int r = 0; r < 4; r++){
        const int mm = m0 + wm*32 + fm*16 + lg*4 + r;
        const int bb = mm >> 11, s = mm & 2047;
        const float v = acc[fm*4+fn][r] + bi;
        if (c < 48){
          Q[(((long)(bb*HH + h))*SS + s)*HD + c] = f2bf(v);
        } else if (c < 96){
          Kd[(((long)(bb*HH + h))*SS + s)*HD + (c-48)] = f2bf(v);
        } else {
          // V transposed: [B,H,48,S]
          Vt[(((long)(bb*HH + h))*HD + (c-96))*SS + s] = f2bf(v);
        }
      }
    }
  }
}

// ---------------- Kernel 2: MFMA attention with head-softmax ----------------
// Block: one (b, 16-query tile). 8 waves = 8 heads. V^T global layout makes
// the V staging a straight wide copy (no in-LDS transpose).
__global__ __launch_bounds__(512, 4) void attn_kernel(
    const u16* __restrict__ Q, const u16* __restrict__ K,
    const u16* __restrict__ Vg, float* __restrict__ vals)
{
  __shared__ float Ss[HH][QT][36];   // scores f32 [h][q][k]
  __shared__ u16  Pb[HH][QT][40];    // P bf16 [h][q][k] (MFMA A layout)
  __shared__ u16  Vt[HH][HD][40];    // V^T bf16 [h][d][k]

  const int tid  = threadIdx.x;
  const int w    = tid >> 6;
  const int lane = tid & 63;
  const int h    = w;
  const int b    = blockIdx.x >> 7;
  const int qt   = blockIdx.x & 127;
  const int q0   = qt * QT;
  const int lg   = lane >> 4;
  const int ln   = lane & 15;

  const long hbase = ((long)(b*HH + h)) * SS;

  // Q fragments (A operand), held for the whole kernel.
  s16x8 qf0, qf1;
  {
    const u16* qp = Q + (hbase + q0 + ln)*HD;
    qf0 = *(const s16x8*)(qp + lg*8);
    if (lane < 32) qf1 = *(const s16x8*)(qp + 32 + lg*8);
    else           qf1 = (s16x8){0,0,0,0,0,0,0,0};
  }

  f32x4 oacc[3];
  #pragma unroll
  for (int i = 0; i < 3; i++) oacc[i] = (f32x4){0.f,0.f,0.f,0.f};

  const float scale = 0.14433756729740643f;  // 1/sqrt(48)

  const int sq = tid >> 5, sk = tid & 31;
  // V staging: 1536 16B-chunks (8h x 48d x 4oct), 3 per thread
  int sh[3], sd[3], so[3];
  #pragma unroll
  for (int i = 0; i < 3; i++){
    const int c = tid + i*512;
    sh[i] = c / 192;
    const int rem = c % 192;
    sd[i] = rem >> 2;
    so[i] = (rem & 3) * 8;
  }

  for (int kt = 0; kt < SS/KT; kt++){
    const int k0 = kt * KT;
    __syncthreads();   // prev PV done with Pb/Vt; prev softmax done with Ss

    // --- QK^T: S[h][16q][32k] per wave ---
    #pragma unroll
    for (int nt = 0; nt < 2; nt++){
      const u16* kp = K + (hbase + k0 + nt*16 + ln)*HD;
      s16x8 kf0 = *(const s16x8*)(kp + lg*8);
      s16x8 kf1;
      if (lane < 32) kf1 = *(const s16x8*)(kp + 32 + lg*8);
      else           kf1 = (s16x8){0,0,0,0,0,0,0,0};
      f32x4 a = (f32x4){0.f,0.f,0.f,0.f};
      a = __builtin_amdgcn_mfma_f32_16x16x32_bf16(qf0, kf0, a, 0, 0, 0);
      a = __builtin_amdgcn_mfma_f32_16x16x32_bf16(qf1, kf1, a, 0, 0, 0);
      #pragma unroll
      for (int r = 0; r < 4; r++)
        Ss[h][lg*4 + r][nt*16 + ln] = a[r] * scale;
    }

    // --- stage V^T tile: straight wide copy, 3 x 16B per thread ---
    #pragma unroll
    for (int i = 0; i < 3; i++){
      u16x8 v = *(const u16x8*)(Vg + ((long)(b*HH + sh[i])*HD + sd[i])*SS + k0 + so[i]);
      *(u16x8*)&Vt[sh[i]][sd[i]][so[i]] = v;
    }
    __syncthreads();

    // --- softmax over the 8 heads for my (q,k) ---
    {
      float s0 = Ss[0][sq][sk], s1 = Ss[1][sq][sk];
      float s2 = Ss[2][sq][sk], s3 = Ss[3][sq][sk];
      float s4 = Ss[4][sq][sk], s5 = Ss[5][sq][sk];
      float s6 = Ss[6][sq][sk], s7 = Ss[7][sq][sk];
      float m = fmaxf(fmaxf(fmaxf(s0,s1), fmaxf(s2,s3)),
                      fmaxf(fmaxf(s4,s5), fmaxf(s6,s7)));
      float e0 = __expf(s0-m), e1 = __expf(s1-m), e2 = __expf(s2-m), e3 = __expf(s3-m);
      float e4 = __expf(s4-m), e5 = __expf(s5-m), e6 = __expf(s6-m), e7 = __expf(s7-m);
      float rs = 1.f / (e0+e1+e2+e3+e4+e5+e6+e7);
      Pb[0][sq][sk] = f2bf(e0*rs); Pb[1][sq][sk] = f2bf(e1*rs);
      Pb[2][sq][sk] = f2bf(e2*rs); Pb[3][sq][sk] = f2bf(e3*rs);
      Pb[4][sq][sk] = f2bf(e4*rs); Pb[5][sq][sk] = f2bf(e5*rs);
      Pb[6][sq][sk] = f2bf(e6*rs); Pb[7][sq][sk] = f2bf(e7*rs);
    }
    __syncthreads();

    // --- PV: O[16q][48d] += P[16q][32k] * V[32k][48d] ---
    {
      s16x8 pf = *(const s16x8*)&Pb[h][ln][lg*8];
      #pragma unroll
      for (int nt = 0; nt < 3; nt++){
        s16x8 vf = *(const s16x8*)&Vt[h][nt*16 + ln][lg*8];
        oacc[nt] = __builtin_amdgcn_mfma_f32_16x16x32_bf16(pf, vf, oacc[nt], 0, 0, 0);
      }
    }
  }

  // store vals[b][h][q][d] fp32 (bug-compatible flat layout)
  float* op = vals + (hbase + q0)*HD;
  #pragma unroll
  for (int nt = 0; nt < 3; nt++)
    #pragma unroll
    for (int r = 0; r < 4; r++)
      op[(long)(lg*4 + r)*HD + nt*16 + ln] = oacc[nt][r];
}

// ---------------- Kernel 3: output projection, split-bf16 MFMA GEMM ----------------
__global__ __launch_bounds__(512, 4) void out_gemm(
    const float* __restrict__ A, const float* __restrict__ W,
    const float* __restrict__ bias, float* __restrict__ out)
{
  __shared__ u16 Ah[128][40], Al[128][40], Bh[128][40], Bl[128][40];
  const int tid  = threadIdx.x;
  const int w    = tid >> 6, lane = tid & 63;
  const int lg   = lane >> 4, ln = lane & 15;
  const int wm   = w >> 1, wn = w & 1;
  const int mb   = blockIdx.x / 3, nb = blockIdx.x % 3;
  const int m0   = mb * 128, n0 = nb * 128;
  const int srow = tid >> 3, sk4 = (tid & 7) << 2;

  f32x4 acc[8];
  #pragma unroll
  for (int i = 0; i < 8; i++) acc[i] = (f32x4){0.f,0.f,0.f,0.f};

  for (int ks = 0; ks < 12; ks++){
    const int k0 = ks * 32;
    __syncthreads();
    #pragma unroll
    for (int p = 0; p < 2; p++){
      const int row = srow + p*64;
      float4 av = *(const float4*)(A + (long)(m0+row)*DD + k0 + sk4);
      float4 bv = *(const float4*)(W + (long)(n0+row)*DD + k0 + sk4);
      u16 h0,l0,h1,l1,h2,l2,h3,l3;
      split2(av.x,h0,l0); split2(av.y,h1,l1); split2(av.z,h2,l2); split2(av.w,h3,l3);
      *(u16x4*)&Ah[row][sk4] = (u16x4){h0,h1,h2,h3};
      *(u16x4*)&Al[row][sk4] = (u16x4){l0,l1,l2,l3};
      split2(bv.x,h0,l0); split2(bv.y,h1,l1); split2(bv.z,h2,l2); split2(bv.w,h3,l3);
      *(u16x4*)&Bh[row][sk4] = (u16x4){h0,h1,h2,h3};
      *(u16x4*)&Bl[row][sk4] = (u16x4){l0,l1,l2,l3};
    }
    __syncthreads();
    s16x8 bh[4], bl[4];
    #pragma unroll
    for (int fn = 0; fn < 4; fn++){
      const int br = wn*64 + fn*16 + ln;
      bh[fn] = *(const s16x8*)&Bh[br][lg*8];
      bl[fn] = *(const s16x8*)&Bl[br][lg*8];
    }
    #pragma unroll
    for (int fm = 0; fm < 2; fm++){
      const int ar = wm*32 + fm*16 + ln;
      s16x8 ah = *(const s16x8*)&Ah[ar][lg*8];
      s16x8 al = *(const s16x8*)&Al[ar][lg*8];
      #pragma unroll
      for (int fn = 0; fn < 4; fn++){
        f32x4 c = acc[fm*4+fn];
        c = __builtin_amdgcn_mfma_f32_16x16x32_bf16(ah, bh[fn], c, 0, 0, 0);
        c = __builtin_amdgcn_mfma_f32_16x16x32_bf16(ah, bl[fn], c, 0, 0, 0);
        c = __builtin_amdgcn_mfma_f32_16x16x32_bf16(al, bh[fn], c, 0, 0, 0);
        acc[fm*4+fn] = c;
      }
    }
  }
  #pragma unroll
  for (int fm = 0; fm < 2; fm++){
    #pragma unroll
    for (int fn = 0; fn < 4; fn++){
      const int e = n0 + wn*64 + fn*16 + ln;
      const float bi = bias[e];
      #pragma unroll
      for (int r = 0; r < 4; r++){
        const int mm = m0 + wm*32 + fm*16 + lg*4 + r;
        out[(long)mm*DD + e] = acc[fm*4+fn][r] + bi;
      }
    }
  }
}

extern "C" void kernel_launch(void* const* d_in, const int* in_sizes, int n_in,
                              void* d_out, int out_size, void* d_ws, size_t ws_size,
                              hipStream_t stream)
{
  const float* x    = (const float*)d_in[0];
  const float* Wqkv = (const float*)d_in[1];
  const float* bqkv = (const float*)d_in[2];
  const float* Wo   = (const float*)d_in[3];
  const float* bo   = (const float*)d_in[4];
  float* out = (float*)d_out;

  const size_t QSZ = (size_t)BB*HH*SS*HD;   // 6,291,456 elems
  u16* Q  = (u16*)d_ws;
  u16* K  = Q + QSZ;
  u16* Vt = K + QSZ;                        // V^T [B,H,48,S]
  float* vals = (float*)(Vt + QSZ);         // fp32, 25.2 MB

  qkv_gemm<<<1152, 512, 0, stream>>>(x, Wqkv, bqkv, Q, K, Vt);
  attn_kernel<<<1024, 512, 0, stream>>>(Q, K, Vt, vals);
  out_gemm<<<384, 512, 0, stream>>>(vals, Wo, bo, out);
}

// Round 4
// 353.200 us; speedup vs baseline: 6.4126x; 1.0007x over previous
//
#include <hip/hip_runtime.h>
#include <hip/hip_bf16.h>

#define BB 8
#define SS 2048
#define DD 384
#define HH 8
#define HD 48
#define QT 16
#define KT 32

typedef unsigned short u16;
typedef unsigned short u16x4 __attribute__((ext_vector_type(4)));
typedef unsigned short u16x8 __attribute__((ext_vector_type(8)));
typedef short s16x8 __attribute__((ext_vector_type(8)));
typedef float f32x4 __attribute__((ext_vector_type(4)));

__device__ __forceinline__ float bf2f(u16 v){
  union { unsigned int u; float f; } x; x.u = ((unsigned int)v) << 16; return x.f;
}
__device__ __forceinline__ u16 f2bf(float f){
  union { float f; unsigned int u; } x; x.f = f;
  unsigned int r = x.u + 0x7fffu + ((x.u >> 16) & 1u);
  return (u16)(r >> 16);
}
// split fp32 into hi (truncated bf16) + lo (bf16 of residual); hi+lo ~ 17-bit mantissa
__device__ __forceinline__ void split2(float f, u16& h, u16& l){
  union { float f; unsigned int u; } x; x.f = f;
  h = (u16)(x.u >> 16);
  l = f2bf(f - bf2f(h));
}

// ---------------- Kernel 1: QKV projection, split-bf16 MFMA GEMM ----------------
// C[16384 x 1152] = x[16384 x 384] * Wqkv^T ; scatter to Q (pre-scaled by
// 1/sqrt(48)), K ([B,H,S,48]) and V^T ([B,H,48,S]) bf16 with bias.
__global__ __launch_bounds__(512, 4) void qkv_gemm(
    const float* __restrict__ x, const float* __restrict__ W,
    const float* __restrict__ bias,
    u16* __restrict__ Q, u16* __restrict__ Kd, u16* __restrict__ Vt)
{
  __shared__ u16 Ah[128][40], Al[128][40], Bh[128][40], Bl[128][40];
  const int tid  = threadIdx.x;
  const int w    = tid >> 6, lane = tid & 63;
  const int lg   = lane >> 4, ln = lane & 15;
  const int wm   = w >> 1, wn = w & 1;
  const int mb   = blockIdx.x / 9, nb = blockIdx.x % 9;
  const int m0   = mb * 128, n0 = nb * 128;
  const int srow = tid >> 3, sk4 = (tid & 7) << 2;
  const float qscale = 0.14433756729740643f;  // 1/sqrt(48)

  f32x4 acc[8];
  #pragma unroll
  for (int i = 0; i < 8; i++) acc[i] = (f32x4){0.f,0.f,0.f,0.f};

  for (int ks = 0; ks < 12; ks++){
    const int k0 = ks * 32;
    __syncthreads();
    #pragma unroll
    for (int p = 0; p < 2; p++){
      const int row = srow + p*64;
      float4 av = *(const float4*)(x + (long)(m0+row)*DD + k0 + sk4);
      float4 bv = *(const float4*)(W + (long)(n0+row)*DD + k0 + sk4);
      u16 h0,l0,h1,l1,h2,l2,h3,l3;
      split2(av.x,h0,l0); split2(av.y,h1,l1); split2(av.z,h2,l2); split2(av.w,h3,l3);
      *(u16x4*)&Ah[row][sk4] = (u16x4){h0,h1,h2,h3};
      *(u16x4*)&Al[row][sk4] = (u16x4){l0,l1,l2,l3};
      split2(bv.x,h0,l0); split2(bv.y,h1,l1); split2(bv.z,h2,l2); split2(bv.w,h3,l3);
      *(u16x4*)&Bh[row][sk4] = (u16x4){h0,h1,h2,h3};
      *(u16x4*)&Bl[row][sk4] = (u16x4){l0,l1,l2,l3};
    }
    __syncthreads();
    s16x8 bh[4], bl[4];
    #pragma unroll
    for (int fn = 0; fn < 4; fn++){
      const int br = wn*64 + fn*16 + ln;
      bh[fn] = *(const s16x8*)&Bh[br][lg*8];
      bl[fn] = *(const s16x8*)&Bl[br][lg*8];
    }
    #pragma unroll
    for (int fm = 0; fm < 2; fm++){
      const int ar = wm*32 + fm*16 + ln;
      s16x8 ah = *(const s16x8*)&Ah[ar][lg*8];
      s16x8 al = *(const s16x8*)&Al[ar][lg*8];
      #pragma unroll
      for (int fn = 0; fn < 4; fn++){
        f32x4 c = acc[fm*4+fn];
        c = __builtin_amdgcn_mfma_f32_16x16x32_bf16(ah, bh[fn], c, 0, 0, 0);
        c = __builtin_amdgcn_mfma_f32_16x16x32_bf16(ah, bl[fn], c, 0, 0, 0);
        c = __builtin_amdgcn_mfma_f32_16x16x32_bf16(al, bh[fn], c, 0, 0, 0);
        acc[fm*4+fn] = c;
      }
    }
  }
  // epilogue: row = lg*4+r (M=token), col = ln (N=e); scatter
  #pragma unroll
  for (int fm = 0; fm < 2; fm++){
    #pragma unroll
    for (int fn = 0; fn < 4; fn++){
      const int e = n0 + wn*64 + fn*16 + ln;
      const float bi = bias[e];
      const int h = e / 144, c = e % 144;
      #pragma unroll
      for (int r = 0; r < 4; r++){
        const int mm = m0 + wm*32 + fm*16 + lg*4 + r;
        const int bb = mm >> 11, s = mm & 2047;
        const float v = acc[fm*4+fn][r] + bi;
        if (c < 48){
          Q[(((long)(bb*HH + h))*SS + s)*HD + c] = f2bf(v * qscale);
        } else if (c < 96){
          Kd[(((long)(bb*HH + h))*SS + s)*HD + (c-48)] = f2bf(v);
        } else {
          // V transposed: [B,H,48,S]
          Vt[(((long)(bb*HH + h))*HD + (c-96))*SS + s] = f2bf(v);
        }
      }
    }
  }
}

// ---------------- Kernel 2: MFMA attention with head-softmax ----------------
// Block: one (b, 16-query tile). 8 waves = 8 heads.
// QK^T with swapped operands -> D[k][q] -> wide f32x4 score writes.
// V consumed directly from global V^T as PV B-fragments (no LDS for V).
__global__ __launch_bounds__(512, 4) void attn_kernel(
    const u16* __restrict__ Q, const u16* __restrict__ K,
    const u16* __restrict__ Vg, float* __restrict__ vals)
{
  __shared__ float Ss[HH][QT][36];   // scores f32 [h][q][k] (k-contig writes)
  __shared__ u16  Pb[HH][QT][40];    // P bf16 [h][q][k] (MFMA A layout)

  const int tid  = threadIdx.x;
  const int w    = tid >> 6;
  const int lane = tid & 63;
  const int h    = w;
  const int b    = blockIdx.x >> 7;
  const int qt   = blockIdx.x & 127;
  const int q0   = qt * QT;
  const int lg   = lane >> 4;
  const int ln   = lane & 15;

  const long hbase = ((long)(b*HH + h)) * SS;
  const u16* vbase = Vg + ((long)(b*HH + h)) * HD * SS;

  // Q fragments (B operand for swapped QK^T), held for the whole kernel.
  // Q was pre-scaled by 1/sqrt(48) in qkv_gemm.
  s16x8 qf0, qf1;
  {
    const u16* qp = Q + (hbase + q0 + ln)*HD;
    qf0 = *(const s16x8*)(qp + lg*8);
    if (lane < 32) qf1 = *(const s16x8*)(qp + 32 + lg*8);
    else           qf1 = (s16x8){0,0,0,0,0,0,0,0};
  }

  f32x4 oacc[3];
  #pragma unroll
  for (int i = 0; i < 3; i++) oacc[i] = (f32x4){0.f,0.f,0.f,0.f};

  const int sq = tid >> 5, sk = tid & 31;

  for (int kt = 0; kt < SS/KT; kt++){
    const int k0 = kt * KT;
    __syncthreads();   // prev softmax done reading Ss; prev PV done reading Pb

    // --- QK^T (swapped): D[k][q] per wave; f32x4 = 4 consecutive k ---
    #pragma unroll
    for (int nt = 0; nt < 2; nt++){
      const u16* kp = K + (hbase + k0 + nt*16 + ln)*HD;
      s16x8 kf0 = *(const s16x8*)(kp + lg*8);
      s16x8 kf1;
      if (lane < 32) kf1 = *(const s16x8*)(kp + 32 + lg*8);
      else           kf1 = (s16x8){0,0,0,0,0,0,0,0};
      f32x4 a = (f32x4){0.f,0.f,0.f,0.f};
      a = __builtin_amdgcn_mfma_f32_16x16x32_bf16(kf0, qf0, a, 0, 0, 0);
      a = __builtin_amdgcn_mfma_f32_16x16x32_bf16(kf1, qf1, a, 0, 0, 0);
      // rows k = lg*4+r, col q = ln  ->  one b128 per nt
      *(f32x4*)&Ss[h][ln][nt*16 + lg*4] = a;
    }
    __syncthreads();

    // --- softmax over the 8 heads for my (q,k) ---
    {
      float s0 = Ss[0][sq][sk], s1 = Ss[1][sq][sk];
      float s2 = Ss[2][sq][sk], s3 = Ss[3][sq][sk];
      float s4 = Ss[4][sq][sk], s5 = Ss[5][sq][sk];
      float s6 = Ss[6][sq][sk], s7 = Ss[7][sq][sk];
      float m = fmaxf(fmaxf(fmaxf(s0,s1), fmaxf(s2,s3)),
                      fmaxf(fmaxf(s4,s5), fmaxf(s6,s7)));
      float e0 = __expf(s0-m), e1 = __expf(s1-m), e2 = __expf(s2-m), e3 = __expf(s3-m);
      float e4 = __expf(s4-m), e5 = __expf(s5-m), e6 = __expf(s6-m), e7 = __expf(s7-m);
      float rs = 1.f / (e0+e1+e2+e3+e4+e5+e6+e7);
      Pb[0][sq][sk] = f2bf(e0*rs); Pb[1][sq][sk] = f2bf(e1*rs);
      Pb[2][sq][sk] = f2bf(e2*rs); Pb[3][sq][sk] = f2bf(e3*rs);
      Pb[4][sq][sk] = f2bf(e4*rs); Pb[5][sq][sk] = f2bf(e5*rs);
      Pb[6][sq][sk] = f2bf(e6*rs); Pb[7][sq][sk] = f2bf(e7*rs);
    }
    __syncthreads();

    // --- PV: O[16q][48d] += P[16q][32k] * V[32k][48d], V^T from global ---
    {
      s16x8 pf = *(const s16x8*)&Pb[h][ln][lg*8];
      #pragma unroll
      for (int c = 0; c < 3; c++){
        // B-frag: V[k=lg*8+i][d=c*16+ln] = V^T[d][k] contiguous in k
        s16x8 vf = *(const s16x8*)(vbase + (long)(c*16 + ln)*SS + k0 + lg*8);
        oacc[c] = __builtin_amdgcn_mfma_f32_16x16x32_bf16(pf, vf, oacc[c], 0, 0, 0);
      }
    }
  }

  // store vals[b][h][q][d] fp32 (bug-compatible flat layout)
  float* op = vals + (hbase + q0)*HD;
  #pragma unroll
  for (int c = 0; c < 3; c++)
    #pragma unroll
    for (int r = 0; r < 4; r++)
      op[(long)(lg*4 + r)*HD + c*16 + ln] = oacc[c][r];
}

// ---------------- Kernel 3: output projection, split-bf16 MFMA GEMM ----------------
__global__ __launch_bounds__(512, 4) void out_gemm(
    const float* __restrict__ A, const float* __restrict__ W,
    const float* __restrict__ bias, float* __restrict__ out)
{
  __shared__ u16 Ah[128][40], Al[128][40], Bh[128][40], Bl[128][40];
  const int tid  = threadIdx.x;
  const int w    = tid >> 6, lane = tid & 63;
  const int lg   = lane >> 4, ln = lane & 15;
  const int wm   = w >> 1, wn = w & 1;
  const int mb   = blockIdx.x / 3, nb = blockIdx.x % 3;
  const int m0   = mb * 128, n0 = nb * 128;
  const int srow = tid >> 3, sk4 = (tid & 7) << 2;

  f32x4 acc[8];
  #pragma unroll
  for (int i = 0; i < 8; i++) acc[i] = (f32x4){0.f,0.f,0.f,0.f};

  for (int ks = 0; ks < 12; ks++){
    const int k0 = ks * 32;
    __syncthreads();
    #pragma unroll
    for (int p = 0; p < 2; p++){
      const int row = srow + p*64;
      float4 av = *(const float4*)(A + (long)(m0+row)*DD + k0 + sk4);
      float4 bv = *(const float4*)(W + (long)(n0+row)*DD + k0 + sk4);
      u16 h0,l0,h1,l1,h2,l2,h3,l3;
      split2(av.x,h0,l0); split2(av.y,h1,l1); split2(av.z,h2,l2); split2(av.w,h3,l3);
      *(u16x4*)&Ah[row][sk4] = (u16x4){h0,h1,h2,h3};
      *(u16x4*)&Al[row][sk4] = (u16x4){l0,l1,l2,l3};
      split2(bv.x,h0,l0); split2(bv.y,h1,l1); split2(bv.z,h2,l2); split2(bv.w,h3,l3);
      *(u16x4*)&Bh[row][sk4] = (u16x4){h0,h1,h2,h3};
      *(u16x4*)&Bl[row][sk4] = (u16x4){l0,l1,l2,l3};
    }
    __syncthreads();
    s16x8 bh[4], bl[4];
    #pragma unroll
    for (int fn = 0; fn < 4; fn++){
      const int br = wn*64 + fn*16 + ln;
      bh[fn] = *(const s16x8*)&Bh[br][lg*8];
      bl[fn] = *(const s16x8*)&Bl[br][lg*8];
    }
    #pragma unroll
    for (int fm = 0; fm < 2; fm++){
      const int ar = wm*32 + fm*16 + ln;
      s16x8 ah = *(const s16x8*)&Ah[ar][lg*8];
      s16x8 al = *(const s16x8*)&Al[ar][lg*8];
      #pragma unroll
      for (int fn = 0; fn < 4; fn++){
        f32x4 c = acc[fm*4+fn];
        c = __builtin_amdgcn_mfma_f32_16x16x32_bf16(ah, bh[fn], c, 0, 0, 0);
        c = __builtin_amdgcn_mfma_f32_16x16x32_bf16(ah, bl[fn], c, 0, 0, 0);
        c = __builtin_amdgcn_mfma_f32_16x16x32_bf16(al, bh[fn], c, 0, 0, 0);
        acc[fm*4+fn] = c;
      }
    }
  }
  #pragma unroll
  for (int fm = 0; fm < 2; fm++){
    #pragma unroll
    for (int fn = 0; fn < 4; fn++){
      const int e = n0 + wn*64 + fn*16 + ln;
      const float bi = bias[e];
      #pragma unroll
      for (int r = 0; r < 4; r++){
        const int mm = m0 + wm*32 + fm*16 + lg*4 + r;
        out[(long)mm*DD + e] = acc[fm*4+fn][r] + bi;
      }
    }
  }
}

extern "C" void kernel_launch(void* const* d_in, const int* in_sizes, int n_in,
                              void* d_out, int out_size, void* d_ws, size_t ws_size,
                              hipStream_t stream)
{
  const float* x    = (const float*)d_in[0];
  const float* Wqkv = (const float*)d_in[1];
  const float* bqkv = (const float*)d_in[2];
  const float* Wo   = (const float*)d_in[3];
  const float* bo   = (const float*)d_in[4];
  float* out = (float*)d_out;

  const size_t QSZ = (size_t)BB*HH*SS*HD;   // 6,291,456 elems
  u16* Q  = (u16*)d_ws;
  u16* K  = Q + QSZ;
  u16* Vt = K + QSZ;                        // V^T [B,H,48,S]
  float* vals = (float*)(Vt + QSZ);         // fp32, 25.2 MB

  qkv_gemm<<<1152, 512, 0, stream>>>(x, Wqkv, bqkv, Q, K, Vt);
  attn_kernel<<<1024, 512, 0, stream>>>(Q, K, Vt, vals);
  out_gemm<<<384, 512, 0, stream>>>(vals, Wo, bo, out);
}

// Round 5
// 262.297 us; speedup vs baseline: 8.6350x; 1.3466x over previous
//
#include <hip/hip_runtime.h>
#include <hip/hip_bf16.h>

#define BB 8
#define SS 2048
#define DD 384
#define HH 8
#define HD 48
#define QT 32
#define KT 32

typedef unsigned short u16;
typedef unsigned short u16x4 __attribute__((ext_vector_type(4)));
typedef unsigned short u16x8 __attribute__((ext_vector_type(8)));
typedef short s16x8 __attribute__((ext_vector_type(8)));
typedef float f32x4 __attribute__((ext_vector_type(4)));

__device__ __forceinline__ float bf2f(u16 v){
  union { unsigned int u; float f; } x; x.u = ((unsigned int)v) << 16; return x.f;
}
__device__ __forceinline__ u16 f2bf(float f){
  union { float f; unsigned int u; } x; x.f = f;
  unsigned int r = x.u + 0x7fffu + ((x.u >> 16) & 1u);
  return (u16)(r >> 16);
}
// truncating bf16 (1 VALU op); used only for P in [0,1] where bias ~2^-9 is invisible
__device__ __forceinline__ u16 f2bf_trunc(float f){
  union { float f; unsigned int u; } x; x.f = f;
  return (u16)(x.u >> 16);
}
// split fp32 into hi (truncated bf16) + lo (bf16 of residual); hi+lo ~ 17-bit mantissa
__device__ __forceinline__ void split2(float f, u16& h, u16& l){
  union { float f; unsigned int u; } x; x.f = f;
  h = (u16)(x.u >> 16);
  l = f2bf(f - bf2f(h));
}

// lgkm-only barrier: LDS writes visible, but global loads stay in flight
#define LBAR() do { \
  asm volatile("s_waitcnt lgkmcnt(0)" ::: "memory"); \
  __builtin_amdgcn_s_barrier(); \
  asm volatile("" ::: "memory"); \
} while (0)

// ---------------- Kernel 1: QKV projection, split-bf16 MFMA GEMM ----------------
// C[16384 x 1152] = x[16384 x 384] * Wqkv^T ; scatter to Q (pre-scaled by
// 1/sqrt(48)), K ([B,H,S,48]) and V^T ([B,H,48,S]) bf16 with bias.
__global__ __launch_bounds__(512, 4) void qkv_gemm(
    const float* __restrict__ x, const float* __restrict__ W,
    const float* __restrict__ bias,
    u16* __restrict__ Q, u16* __restrict__ Kd, u16* __restrict__ Vt)
{
  __shared__ u16 Ah[128][40], Al[128][40], Bh[128][40], Bl[128][40];
  const int tid  = threadIdx.x;
  const int w    = tid >> 6, lane = tid & 63;
  const int lg   = lane >> 4, ln = lane & 15;
  const int wm   = w >> 1, wn = w & 1;
  const int mb   = blockIdx.x / 9, nb = blockIdx.x % 9;
  const int m0   = mb * 128, n0 = nb * 128;
  const int srow = tid >> 3, sk4 = (tid & 7) << 2;
  const float qscale = 0.14433756729740643f;  // 1/sqrt(48)

  f32x4 acc[8];
  #pragma unroll
  for (int i = 0; i < 8; i++) acc[i] = (f32x4){0.f,0.f,0.f,0.f};

  for (int ks = 0; ks < 12; ks++){
    const int k0 = ks * 32;
    __syncthreads();
    #pragma unroll
    for (int p = 0; p < 2; p++){
      const int row = srow + p*64;
      float4 av = *(const float4*)(x + (long)(m0+row)*DD + k0 + sk4);
      float4 bv = *(const float4*)(W + (long)(n0+row)*DD + k0 + sk4);
      u16 h0,l0,h1,l1,h2,l2,h3,l3;
      split2(av.x,h0,l0); split2(av.y,h1,l1); split2(av.z,h2,l2); split2(av.w,h3,l3);
      *(u16x4*)&Ah[row][sk4] = (u16x4){h0,h1,h2,h3};
      *(u16x4*)&Al[row][sk4] = (u16x4){l0,l1,l2,l3};
      split2(bv.x,h0,l0); split2(bv.y,h1,l1); split2(bv.z,h2,l2); split2(bv.w,h3,l3);
      *(u16x4*)&Bh[row][sk4] = (u16x4){h0,h1,h2,h3};
      *(u16x4*)&Bl[row][sk4] = (u16x4){l0,l1,l2,l3};
    }
    __syncthreads();
    s16x8 bh[4], bl[4];
    #pragma unroll
    for (int fn = 0; fn < 4; fn++){
      const int br = wn*64 + fn*16 + ln;
      bh[fn] = *(const s16x8*)&Bh[br][lg*8];
      bl[fn] = *(const s16x8*)&Bl[br][lg*8];
    }
    #pragma unroll
    for (int fm = 0; fm < 2; fm++){
      const int ar = wm*32 + fm*16 + ln;
      s16x8 ah = *(const s16x8*)&Ah[ar][lg*8];
      s16x8 al = *(const s16x8*)&Al[ar][lg*8];
      #pragma unroll
      for (int fn = 0; fn < 4; fn++){
        f32x4 c = acc[fm*4+fn];
        c = __builtin_amdgcn_mfma_f32_16x16x32_bf16(ah, bh[fn], c, 0, 0, 0);
        c = __builtin_amdgcn_mfma_f32_16x16x32_bf16(ah, bl[fn], c, 0, 0, 0);
        c = __builtin_amdgcn_mfma_f32_16x16x32_bf16(al, bh[fn], c, 0, 0, 0);
        acc[fm*4+fn] = c;
      }
    }
  }
  // epilogue: row = lg*4+r (M=token), col = ln (N=e); scatter
  #pragma unroll
  for (int fm = 0; fm < 2; fm++){
    #pragma unroll
    for (int fn = 0; fn < 4; fn++){
      const int e = n0 + wn*64 + fn*16 + ln;
      const float bi = bias[e];
      const int h = e / 144, c = e % 144;
      #pragma unroll
      for (int r = 0; r < 4; r++){
        const int mm = m0 + wm*32 + fm*16 + lg*4 + r;
        const int bb = mm >> 11, s = mm & 2047;
        const float v = acc[fm*4+fn][r] + bi;
        if (c < 48){
          Q[(((long)(bb*HH + h))*SS + s)*HD + c] = f2bf(v * qscale);
        } else if (c < 96){
          Kd[(((long)(bb*HH + h))*SS + s)*HD + (c-48)] = f2bf(v);
        } else {
          // V transposed: [B,H,48,S]
          Vt[(((long)(bb*HH + h))*HD + (c-96))*SS + s] = f2bf(v);
        }
      }
    }
  }
}

// ---------------- Kernel 2: MFMA attention with head-softmax ----------------
// Block: one (b, 32-query tile), 8 waves = 8 heads, 2 q-subtiles per wave.
// Per 32-key tile: V frags issued first (in flight across both barriers),
// swapped QK^T -> wide Ss writes, head-softmax (no max subtraction: |s|<~1.5),
// PV from global V^T. Two lgkm-only barriers per iteration.
__global__ __launch_bounds__(512, 4) void attn_kernel(
    const u16* __restrict__ Q, const u16* __restrict__ K,
    const u16* __restrict__ Vg, float* __restrict__ vals)
{
  __shared__ float Ss[HH][QT][36];   // scores f32 [h][q][k]
  __shared__ u16  Pb[HH][QT][40];    // P bf16 [h][q][k] (MFMA A layout)

  const int tid  = threadIdx.x;
  const int h    = tid >> 6;
  const int lane = tid & 63;
  // XCD-chunked swizzle: 512 blocks, 8 XCDs -> XCD x gets exactly batch b=x,
  // making that batch's 3MB of K/V L2-resident.
  const int wg   = ((int)blockIdx.x % 8) * 64 + (int)blockIdx.x / 8;
  const int b    = wg >> 6;
  const int qt   = wg & 63;
  const int q0   = qt * QT;
  const int lg   = lane >> 4;
  const int ln   = lane & 15;

  const long hbase = ((long)(b*HH + h)) * SS;
  const u16* vbase = Vg + ((long)(b*HH + h)) * HD * SS;

  // Q fragments (B operand of swapped QK^T) for both subtiles, held all kernel.
  s16x8 qf0[2], qf1[2];
  #pragma unroll
  for (int qs = 0; qs < 2; qs++){
    const u16* qp = Q + (hbase + q0 + qs*16 + ln)*HD;
    qf0[qs] = *(const s16x8*)(qp + lg*8);
    if (lane < 32) qf1[qs] = *(const s16x8*)(qp + 32 + lg*8);
    else           qf1[qs] = (s16x8){0,0,0,0,0,0,0,0};
  }

  f32x4 oacc[2][3];
  #pragma unroll
  for (int qs = 0; qs < 2; qs++)
    #pragma unroll
    for (int c = 0; c < 3; c++) oacc[qs][c] = (f32x4){0.f,0.f,0.f,0.f};

  const int sq0 = tid >> 5, sk = tid & 31;   // softmax pairs: (sq0,sk),(sq0+16,sk)

  for (int kt = 0; kt < SS/KT; kt++){
    const int k0 = kt * KT;

    // --- V fragments for THIS iter: issued now, consumed after 2 barriers ---
    s16x8 vf[3];
    #pragma unroll
    for (int c = 0; c < 3; c++)
      vf[c] = *(const s16x8*)(vbase + (long)(c*16 + ln)*SS + k0 + lg*8);

    // --- QK^T (swapped): D[k][q]; K frags shared across both q-subtiles ---
    #pragma unroll
    for (int nt = 0; nt < 2; nt++){
      const u16* kp = K + (hbase + k0 + nt*16 + ln)*HD;
      s16x8 kf0 = *(const s16x8*)(kp + lg*8);
      s16x8 kf1;
      if (lane < 32) kf1 = *(const s16x8*)(kp + 32 + lg*8);
      else           kf1 = (s16x8){0,0,0,0,0,0,0,0};
      #pragma unroll
      for (int qs = 0; qs < 2; qs++){
        f32x4 a = (f32x4){0.f,0.f,0.f,0.f};
        a = __builtin_amdgcn_mfma_f32_16x16x32_bf16(kf0, qf0[qs], a, 0, 0, 0);
        a = __builtin_amdgcn_mfma_f32_16x16x32_bf16(kf1, qf1[qs], a, 0, 0, 0);
        *(f32x4*)&Ss[h][qs*16 + ln][nt*16 + lg*4] = a;   // one b128 write
      }
    }
    LBAR();   // A: Ss visible; also orders prev-iter PV Pb-reads vs softmax writes

    // --- softmax over 8 heads; 2 (q,k) pairs per thread; no max needed ---
    #pragma unroll
    for (int i = 0; i < 2; i++){
      const int sq = sq0 + i*16;
      float e0 = __expf(Ss[0][sq][sk]), e1 = __expf(Ss[1][sq][sk]);
      float e2 = __expf(Ss[2][sq][sk]), e3 = __expf(Ss[3][sq][sk]);
      float e4 = __expf(Ss[4][sq][sk]), e5 = __expf(Ss[5][sq][sk]);
      float e6 = __expf(Ss[6][sq][sk]), e7 = __expf(Ss[7][sq][sk]);
      float rs = 1.f / (e0+e1+e2+e3+e4+e5+e6+e7);
      Pb[0][sq][sk] = f2bf_trunc(e0*rs); Pb[1][sq][sk] = f2bf_trunc(e1*rs);
      Pb[2][sq][sk] = f2bf_trunc(e2*rs); Pb[3][sq][sk] = f2bf_trunc(e3*rs);
      Pb[4][sq][sk] = f2bf_trunc(e4*rs); Pb[5][sq][sk] = f2bf_trunc(e5*rs);
      Pb[6][sq][sk] = f2bf_trunc(e6*rs); Pb[7][sq][sk] = f2bf_trunc(e7*rs);
    }
    LBAR();   // B: Pb visible; also orders softmax Ss-reads vs next-iter writes

    // --- PV: V frags shared across both q-subtiles ---
    #pragma unroll
    for (int qs = 0; qs < 2; qs++){
      s16x8 pf = *(const s16x8*)&Pb[h][qs*16 + ln][lg*8];
      #pragma unroll
      for (int c = 0; c < 3; c++)
        oacc[qs][c] = __builtin_amdgcn_mfma_f32_16x16x32_bf16(pf, vf[c], oacc[qs][c], 0, 0, 0);
    }
  }

  // store vals[b][h][q][d] fp32 (bug-compatible flat layout)
  float* op = vals + (hbase + q0)*HD;
  #pragma unroll
  for (int qs = 0; qs < 2; qs++)
    #pragma unroll
    for (int c = 0; c < 3; c++)
      #pragma unroll
      for (int r = 0; r < 4; r++)
        op[(long)(qs*16 + lg*4 + r)*HD + c*16 + ln] = oacc[qs][c][r];
}

// ---------------- Kernel 3: output projection, split-bf16 MFMA GEMM ----------------
__global__ __launch_bounds__(512, 4) void out_gemm(
    const float* __restrict__ A, const float* __restrict__ W,
    const float* __restrict__ bias, float* __restrict__ out)
{
  __shared__ u16 Ah[128][40], Al[128][40], Bh[128][40], Bl[128][40];
  const int tid  = threadIdx.x;
  const int w    = tid >> 6, lane = tid & 63;
  const int lg   = lane >> 4, ln = lane & 15;
  const int wm   = w >> 1, wn = w & 1;
  const int mb   = blockIdx.x / 3, nb = blockIdx.x % 3;
  const int m0   = mb * 128, n0 = nb * 128;
  const int srow = tid >> 3, sk4 = (tid & 7) << 2;

  f32x4 acc[8];
  #pragma unroll
  for (int i = 0; i < 8; i++) acc[i] = (f32x4){0.f,0.f,0.f,0.f};

  for (int ks = 0; ks < 12; ks++){
    const int k0 = ks * 32;
    __syncthreads();
    #pragma unroll
    for (int p = 0; p < 2; p++){
      const int row = srow + p*64;
      float4 av = *(const float4*)(A + (long)(m0+row)*DD + k0 + sk4);
      float4 bv = *(const float4*)(W + (long)(n0+row)*DD + k0 + sk4);
      u16 h0,l0,h1,l1,h2,l2,h3,l3;
      split2(av.x,h0,l0); split2(av.y,h1,l1); split2(av.z,h2,l2); split2(av.w,h3,l3);
      *(u16x4*)&Ah[row][sk4] = (u16x4){h0,h1,h2,h3};
      *(u16x4*)&Al[row][sk4] = (u16x4){l0,l1,l2,l3};
      split2(bv.x,h0,l0); split2(bv.y,h1,l1); split2(bv.z,h2,l2); split2(bv.w,h3,l3);
      *(u16x4*)&Bh[row][sk4] = (u16x4){h0,h1,h2,h3};
      *(u16x4*)&Bl[row][sk4] = (u16x4){l0,l1,l2,l3};
    }
    __syncthreads();
    s16x8 bh[4], bl[4];
    #pragma unroll
    for (int fn = 0; fn < 4; fn++){
      const int br = wn*64 + fn*16 + ln;
      bh[fn] = *(const s16x8*)&Bh[br][lg*8];
      bl[fn] = *(const s16x8*)&Bl[br][lg*8];
    }
    #pragma unroll
    for (int fm = 0; fm < 2; fm++){
      const int ar = wm*32 + fm*16 + ln;
      s16x8 ah = *(const s16x8*)&Ah[ar][lg*8];
      s16x8 al = *(const s16x8*)&Al[ar][lg*8];
      #pragma unroll
      for (int fn = 0; fn < 4; fn++){
        f32x4 c = acc[fm*4+fn];
        c = __builtin_amdgcn_mfma_f32_16x16x32_bf16(ah, bh[fn], c, 0, 0, 0);
        c = __builtin_amdgcn_mfma_f32_16x16x32_bf16(ah, bl[fn], c, 0, 0, 0);
        c = __builtin_amdgcn_mfma_f32_16x16x32_bf16(al, bh[fn], c, 0, 0, 0);
        acc[fm*4+fn] = c;
      }
    }
  }
  #pragma unroll
  for (int fm = 0; fm < 2; fm++){
    #pragma unroll
    for (int fn = 0; fn < 4; fn++){
      const int e = n0 + wn*64 + fn*16 + ln;
      const float bi = bias[e];
      #pragma unroll
      for (int r = 0; r < 4; r++){
        const int mm = m0 + wm*32 + fm*16 + lg*4 + r;
        out[(long)mm*DD + e] = acc[fm*4+fn][r] + bi;
      }
    }
  }
}

extern "C" void kernel_launch(void* const* d_in, const int* in_sizes, int n_in,
                              void* d_out, int out_size, void* d_ws, size_t ws_size,
                              hipStream_t stream)
{
  const float* x    = (const float*)d_in[0];
  const float* Wqkv = (const float*)d_in[1];
  const float* bqkv = (const float*)d_in[2];
  const float* Wo   = (const float*)d_in[3];
  const float* bo   = (const float*)d_in[4];
  float* out = (float*)d_out;

  const size_t QSZ = (size_t)BB*HH*SS*HD;   // 6,291,456 elems
  u16* Q  = (u16*)d_ws;
  u16* K  = Q + QSZ;
  u16* Vt = K + QSZ;                        // V^T [B,H,48,S]
  float* vals = (float*)(Vt + QSZ);         // fp32, 25.2 MB

  qkv_gemm<<<1152, 512, 0, stream>>>(x, Wqkv, bqkv, Q, K, Vt);
  attn_kernel<<<512, 512, 0, stream>>>(Q, K, Vt, vals);
  out_gemm<<<384, 512, 0, stream>>>(vals, Wo, bo, out);
}

// Round 6
// 222.677 us; speedup vs baseline: 10.1714x; 1.1779x over previous
//
#include <hip/hip_runtime.h>
#include <hip/hip_bf16.h>

#define BB 8
#define SS 2048
#define DD 384
#define HH 8
#define HD 48
#define QT 32
#define KT 32

typedef unsigned short u16;
typedef unsigned short u16x4 __attribute__((ext_vector_type(4)));
typedef unsigned short u16x8 __attribute__((ext_vector_type(8)));
typedef short s16x8 __attribute__((ext_vector_type(8)));
typedef float f32x4 __attribute__((ext_vector_type(4)));

__device__ __forceinline__ float bf2f(u16 v){
  union { unsigned int u; float f; } x; x.u = ((unsigned int)v) << 16; return x.f;
}
__device__ __forceinline__ u16 f2bf(float f){
  union { float f; unsigned int u; } x; x.f = f;
  unsigned int r = x.u + 0x7fffu + ((x.u >> 16) & 1u);
  return (u16)(r >> 16);
}
// truncating bf16 (1 VALU op); used only for P in [0,1] where bias ~2^-9 is invisible
__device__ __forceinline__ u16 f2bf_trunc(float f){
  union { float f; unsigned int u; } x; x.f = f;
  return (u16)(x.u >> 16);
}
// split fp32 into hi (truncated bf16) + lo (bf16 of residual); hi+lo ~ 17-bit mantissa
__device__ __forceinline__ void split2(float f, u16& h, u16& l){
  union { float f; unsigned int u; } x; x.f = f;
  h = (u16)(x.u >> 16);
  l = f2bf(f - bf2f(h));
}

// lgkm-only barrier: LDS writes visible, but global loads stay in flight
#define LBAR() do { \
  asm volatile("s_waitcnt lgkmcnt(0)" ::: "memory"); \
  __builtin_amdgcn_s_barrier(); \
  asm volatile("" ::: "memory"); \
} while (0)

// ---------------- Kernel 1: QKV projection, split-bf16 MFMA GEMM ----------------
// C[16384 x 1152] = x[16384 x 384] * Wqkv^T ; scatter to Q (pre-scaled by
// log2(e)/sqrt(48) so attn softmax can use exp2), K ([B,H,S,48]) and
// V^T ([B,H,48,S]) bf16 with bias.
__global__ __launch_bounds__(512, 4) void qkv_gemm(
    const float* __restrict__ x, const float* __restrict__ W,
    const float* __restrict__ bias,
    u16* __restrict__ Q, u16* __restrict__ Kd, u16* __restrict__ Vt)
{
  __shared__ u16 Ah[128][40], Al[128][40], Bh[128][40], Bl[128][40];
  const int tid  = threadIdx.x;
  const int w    = tid >> 6, lane = tid & 63;
  const int lg   = lane >> 4, ln = lane & 15;
  const int wm   = w >> 1, wn = w & 1;
  const int mb   = blockIdx.x / 9, nb = blockIdx.x % 9;
  const int m0   = mb * 128, n0 = nb * 128;
  const int srow = tid >> 3, sk4 = (tid & 7) << 2;
  const float qscale = 0.2082350972f;  // log2(e)/sqrt(48)

  f32x4 acc[8];
  #pragma unroll
  for (int i = 0; i < 8; i++) acc[i] = (f32x4){0.f,0.f,0.f,0.f};

  for (int ks = 0; ks < 12; ks++){
    const int k0 = ks * 32;
    __syncthreads();
    #pragma unroll
    for (int p = 0; p < 2; p++){
      const int row = srow + p*64;
      float4 av = *(const float4*)(x + (long)(m0+row)*DD + k0 + sk4);
      float4 bv = *(const float4*)(W + (long)(n0+row)*DD + k0 + sk4);
      u16 h0,l0,h1,l1,h2,l2,h3,l3;
      split2(av.x,h0,l0); split2(av.y,h1,l1); split2(av.z,h2,l2); split2(av.w,h3,l3);
      *(u16x4*)&Ah[row][sk4] = (u16x4){h0,h1,h2,h3};
      *(u16x4*)&Al[row][sk4] = (u16x4){l0,l1,l2,l3};
      split2(bv.x,h0,l0); split2(bv.y,h1,l1); split2(bv.z,h2,l2); split2(bv.w,h3,l3);
      *(u16x4*)&Bh[row][sk4] = (u16x4){h0,h1,h2,h3};
      *(u16x4*)&Bl[row][sk4] = (u16x4){l0,l1,l2,l3};
    }
    __syncthreads();
    s16x8 bh[4], bl[4];
    #pragma unroll
    for (int fn = 0; fn < 4; fn++){
      const int br = wn*64 + fn*16 + ln;
      bh[fn] = *(const s16x8*)&Bh[br][lg*8];
      bl[fn] = *(const s16x8*)&Bl[br][lg*8];
    }
    #pragma unroll
    for (int fm = 0; fm < 2; fm++){
      const int ar = wm*32 + fm*16 + ln;
      s16x8 ah = *(const s16x8*)&Ah[ar][lg*8];
      s16x8 al = *(const s16x8*)&Al[ar][lg*8];
      #pragma unroll
      for (int fn = 0; fn < 4; fn++){
        f32x4 c = acc[fm*4+fn];
        c = __builtin_amdgcn_mfma_f32_16x16x32_bf16(ah, bh[fn], c, 0, 0, 0);
        c = __builtin_amdgcn_mfma_f32_16x16x32_bf16(ah, bl[fn], c, 0, 0, 0);
        c = __builtin_amdgcn_mfma_f32_16x16x32_bf16(al, bh[fn], c, 0, 0, 0);
        acc[fm*4+fn] = c;
      }
    }
  }
  // epilogue: row = lg*4+r (M=token), col = ln (N=e); scatter
  #pragma unroll
  for (int fm = 0; fm < 2; fm++){
    #pragma unroll
    for (int fn = 0; fn < 4; fn++){
      const int e = n0 + wn*64 + fn*16 + ln;
      const float bi = bias[e];
      const int h = e / 144, c = e % 144;
      #pragma unroll
      for (int r = 0; r < 4; r++){
        const int mm = m0 + wm*32 + fm*16 + lg*4 + r;
        const int bb = mm >> 11, s = mm & 2047;
        const float v = acc[fm*4+fn][r] + bi;
        if (c < 48){
          Q[(((long)(bb*HH + h))*SS + s)*HD + c] = f2bf(v * qscale);
        } else if (c < 96){
          Kd[(((long)(bb*HH + h))*SS + s)*HD + (c-48)] = f2bf(v);
        } else {
          // V transposed: [B,H,48,S]
          Vt[(((long)(bb*HH + h))*HD + (c-96))*SS + s] = f2bf(v);
        }
      }
    }
  }
}

// ---------------- Kernel 2: MFMA attention with head-softmax ----------------
// Block: one (b, 32-query tile), 8 waves = 8 heads, 2 q-subtiles per wave.
// K fragments double-buffered across k-tiles (prefetched one iter ahead);
// V fragments issued at iter top, consumed at iter end. Two lgkm-only
// barriers per iteration keep all global loads in flight across barriers.
// Softmax uses exp2 (log2e folded into Q) + hardware rcp.
__global__ __launch_bounds__(512, 4) void attn_kernel(
    const u16* __restrict__ Q, const u16* __restrict__ K,
    const u16* __restrict__ Vg, float* __restrict__ vals)
{
  __shared__ float Ss[HH][QT][36];   // scores f32 [h][q][k]
  __shared__ u16  Pb[HH][QT][40];    // P bf16 [h][q][k] (MFMA A layout)

  const int tid  = threadIdx.x;
  const int h    = tid >> 6;
  const int lane = tid & 63;
  // XCD-chunked swizzle: 512 blocks, 8 XCDs -> XCD x gets exactly batch b=x.
  const int wg   = ((int)blockIdx.x % 8) * 64 + (int)blockIdx.x / 8;
  const int b    = wg >> 6;
  const int qt   = wg & 63;
  const int q0   = qt * QT;
  const int lg   = lane >> 4;
  const int ln   = lane & 15;

  const long hbase = ((long)(b*HH + h)) * SS;
  const u16* vbase = Vg + ((long)(b*HH + h)) * HD * SS;
  const s16x8 z8 = (s16x8){0,0,0,0,0,0,0,0};

  // Q fragments (B operand of swapped QK^T) for both subtiles, held all kernel.
  s16x8 qf0[2], qf1[2];
  #pragma unroll
  for (int qs = 0; qs < 2; qs++){
    const u16* qp = Q + (hbase + q0 + qs*16 + ln)*HD;
    qf0[qs] = *(const s16x8*)(qp + lg*8);
    if (lane < 32) qf1[qs] = *(const s16x8*)(qp + 32 + lg*8);
    else           qf1[qs] = z8;
  }

  f32x4 oacc[2][3];
  #pragma unroll
  for (int qs = 0; qs < 2; qs++)
    #pragma unroll
    for (int c = 0; c < 3; c++) oacc[qs][c] = (f32x4){0.f,0.f,0.f,0.f};

  const int sq0 = tid >> 5, sk = tid & 31;

  // K fragment double buffer: [buf][nt]; A = d0..31 slice, B = d32..47+pad
  s16x8 kfA[2][2], kfB[2][2];
  int k0 = 0;
  #pragma unroll
  for (int nt = 0; nt < 2; nt++){
    const u16* kp = K + (hbase + nt*16 + ln)*HD;
    kfA[0][nt] = *(const s16x8*)(kp + lg*8);
    if (lane < 32) kfB[0][nt] = *(const s16x8*)(kp + 32 + lg*8);
    else           kfB[0][nt] = z8;
  }

#define STEP(CUR, NXT) { \
    /* V(t) fragments: issued now, consumed after both barriers */ \
    s16x8 vf0 = *(const s16x8*)(vbase + (long)(     ln)*SS + k0 + lg*8); \
    s16x8 vf1 = *(const s16x8*)(vbase + (long)(16 + ln)*SS + k0 + lg*8); \
    s16x8 vf2 = *(const s16x8*)(vbase + (long)(32 + ln)*SS + k0 + lg*8); \
    /* K(t+1) prefetch into buf NXT */ \
    const int knx = (k0 + KT) & (SS - 1); \
    _Pragma("unroll") \
    for (int nt = 0; nt < 2; nt++){ \
      const u16* kp = K + (hbase + knx + nt*16 + ln)*HD; \
      kfA[NXT][nt] = *(const s16x8*)(kp + lg*8); \
      if (lane < 32) kfB[NXT][nt] = *(const s16x8*)(kp + 32 + lg*8); \
      else           kfB[NXT][nt] = z8; \
    } \
    /* QK^T (swapped): D[k][q] from buf CUR */ \
    __builtin_amdgcn_s_setprio(1); \
    _Pragma("unroll") \
    for (int nt = 0; nt < 2; nt++){ \
      _Pragma("unroll") \
      for (int qs = 0; qs < 2; qs++){ \
        f32x4 a = (f32x4){0.f,0.f,0.f,0.f}; \
        a = __builtin_amdgcn_mfma_f32_16x16x32_bf16(kfA[CUR][nt], qf0[qs], a, 0, 0, 0); \
        a = __builtin_amdgcn_mfma_f32_16x16x32_bf16(kfB[CUR][nt], qf1[qs], a, 0, 0, 0); \
        *(f32x4*)&Ss[h][qs*16 + ln][nt*16 + lg*4] = a; \
      } \
    } \
    __builtin_amdgcn_s_setprio(0); \
    LBAR();   /* Ss visible; orders prev PV Pb-reads vs softmax writes */ \
    _Pragma("unroll") \
    for (int i = 0; i < 2; i++){ \
      const int sq = sq0 + i*16; \
      float e0 = __builtin_amdgcn_exp2f(Ss[0][sq][sk]); \
      float e1 = __builtin_amdgcn_exp2f(Ss[1][sq][sk]); \
      float e2 = __builtin_amdgcn_exp2f(Ss[2][sq][sk]); \
      float e3 = __builtin_amdgcn_exp2f(Ss[3][sq][sk]); \
      float e4 = __builtin_amdgcn_exp2f(Ss[4][sq][sk]); \
      float e5 = __builtin_amdgcn_exp2f(Ss[5][sq][sk]); \
      float e6 = __builtin_amdgcn_exp2f(Ss[6][sq][sk]); \
      float e7 = __builtin_amdgcn_exp2f(Ss[7][sq][sk]); \
      float rs = __builtin_amdgcn_rcpf(((e0+e1)+(e2+e3))+((e4+e5)+(e6+e7))); \
      Pb[0][sq][sk] = f2bf_trunc(e0*rs); Pb[1][sq][sk] = f2bf_trunc(e1*rs); \
      Pb[2][sq][sk] = f2bf_trunc(e2*rs); Pb[3][sq][sk] = f2bf_trunc(e3*rs); \
      Pb[4][sq][sk] = f2bf_trunc(e4*rs); Pb[5][sq][sk] = f2bf_trunc(e5*rs); \
      Pb[6][sq][sk] = f2bf_trunc(e6*rs); Pb[7][sq][sk] = f2bf_trunc(e7*rs); \
    } \
    LBAR();   /* Pb visible; orders softmax Ss-reads vs next-iter writes */ \
    __builtin_amdgcn_s_setprio(1); \
    _Pragma("unroll") \
    for (int qs = 0; qs < 2; qs++){ \
      s16x8 pf = *(const s16x8*)&Pb[h][qs*16 + ln][lg*8]; \
      oacc[qs][0] = __builtin_amdgcn_mfma_f32_16x16x32_bf16(pf, vf0, oacc[qs][0], 0, 0, 0); \
      oacc[qs][1] = __builtin_amdgcn_mfma_f32_16x16x32_bf16(pf, vf1, oacc[qs][1], 0, 0, 0); \
      oacc[qs][2] = __builtin_amdgcn_mfma_f32_16x16x32_bf16(pf, vf2, oacc[qs][2], 0, 0, 0); \
    } \
    __builtin_amdgcn_s_setprio(0); \
    k0 = knx; \
  }

  for (int kt2 = 0; kt2 < SS/KT/2; kt2++){
    STEP(0, 1)
    STEP(1, 0)
  }
#undef STEP

  // store vals[b][h][q][d] fp32 (bug-compatible flat layout)
  float* op = vals + (hbase + q0)*HD;
  #pragma unroll
  for (int qs = 0; qs < 2; qs++)
    #pragma unroll
    for (int c = 0; c < 3; c++)
      #pragma unroll
      for (int r = 0; r < 4; r++)
        op[(long)(qs*16 + lg*4 + r)*HD + c*16 + ln] = oacc[qs][c][r];
}

// ---------------- Kernel 3: output projection, split-bf16 MFMA GEMM ----------------
__global__ __launch_bounds__(512, 4) void out_gemm(
    const float* __restrict__ A, const float* __restrict__ W,
    const float* __restrict__ bias, float* __restrict__ out)
{
  __shared__ u16 Ah[128][40], Al[128][40], Bh[128][40], Bl[128][40];
  const int tid  = threadIdx.x;
  const int w    = tid >> 6, lane = tid & 63;
  const int lg   = lane >> 4, ln = lane & 15;
  const int wm   = w >> 1, wn = w & 1;
  const int mb   = blockIdx.x / 3, nb = blockIdx.x % 3;
  const int m0   = mb * 128, n0 = nb * 128;
  const int srow = tid >> 3, sk4 = (tid & 7) << 2;

  f32x4 acc[8];
  #pragma unroll
  for (int i = 0; i < 8; i++) acc[i] = (f32x4){0.f,0.f,0.f,0.f};

  for (int ks = 0; ks < 12; ks++){
    const int k0 = ks * 32;
    __syncthreads();
    #pragma unroll
    for (int p = 0; p < 2; p++){
      const int row = srow + p*64;
      float4 av = *(const float4*)(A + (long)(m0+row)*DD + k0 + sk4);
      float4 bv = *(const float4*)(W + (long)(n0+row)*DD + k0 + sk4);
      u16 h0,l0,h1,l1,h2,l2,h3,l3;
      split2(av.x,h0,l0); split2(av.y,h1,l1); split2(av.z,h2,l2); split2(av.w,h3,l3);
      *(u16x4*)&Ah[row][sk4] = (u16x4){h0,h1,h2,h3};
      *(u16x4*)&Al[row][sk4] = (u16x4){l0,l1,l2,l3};
      split2(bv.x,h0,l0); split2(bv.y,h1,l1); split2(bv.z,h2,l2); split2(bv.w,h3,l3);
      *(u16x4*)&Bh[row][sk4] = (u16x4){h0,h1,h2,h3};
      *(u16x4*)&Bl[row][sk4] = (u16x4){l0,l1,l2,l3};
    }
    __syncthreads();
    s16x8 bh[4], bl[4];
    #pragma unroll
    for (int fn = 0; fn < 4; fn++){
      const int br = wn*64 + fn*16 + ln;
      bh[fn] = *(const s16x8*)&Bh[br][lg*8];
      bl[fn] = *(const s16x8*)&Bl[br][lg*8];
    }
    #pragma unroll
    for (int fm = 0; fm < 2; fm++){
      const int ar = wm*32 + fm*16 + ln;
      s16x8 ah = *(const s16x8*)&Ah[ar][lg*8];
      s16x8 al = *(const s16x8*)&Al[ar][lg*8];
      #pragma unroll
      for (int fn = 0; fn < 4; fn++){
        f32x4 c = acc[fm*4+fn];
        c = __builtin_amdgcn_mfma_f32_16x16x32_bf16(ah, bh[fn], c, 0, 0, 0);
        c = __builtin_amdgcn_mfma_f32_16x16x32_bf16(ah, bl[fn], c, 0, 0, 0);
        c = __builtin_amdgcn_mfma_f32_16x16x32_bf16(al, bh[fn], c, 0, 0, 0);
        acc[fm*4+fn] = c;
      }
    }
  }
  #pragma unroll
  for (int fm = 0; fm < 2; fm++){
    #pragma unroll
    for (int fn = 0; fn < 4; fn++){
      const int e = n0 + wn*64 + fn*16 + ln;
      const float bi = bias[e];
      #pragma unroll
      for (int r = 0; r < 4; r++){
        const int mm = m0 + wm*32 + fm*16 + lg*4 + r;
        out[(long)mm*DD + e] = acc[fm*4+fn][r] + bi;
      }
    }
  }
}

extern "C" void kernel_launch(void* const* d_in, const int* in_sizes, int n_in,
                              void* d_out, int out_size, void* d_ws, size_t ws_size,
                              hipStream_t stream)
{
  const float* x    = (const float*)d_in[0];
  const float* Wqkv = (const float*)d_in[1];
  const float* bqkv = (const float*)d_in[2];
  const float* Wo   = (const float*)d_in[3];
  const float* bo   = (const float*)d_in[4];
  float* out = (float*)d_out;

  const size_t QSZ = (size_t)BB*HH*SS*HD;   // 6,291,456 elems
  u16* Q  = (u16*)d_ws;
  u16* K  = Q + QSZ;
  u16* Vt = K + QSZ;                        // V^T [B,H,48,S]
  float* vals = (float*)(Vt + QSZ);         // fp32, 25.2 MB

  qkv_gemm<<<1152, 512, 0, stream>>>(x, Wqkv, bqkv, Q, K, Vt);
  attn_kernel<<<512, 512, 0, stream>>>(Q, K, Vt, vals);
  out_gemm<<<384, 512, 0, stream>>>(vals, Wo, bo, out);
}